// Round 12
// baseline (250.283 us; speedup 1.0000x reference)
//
#include <hip/hip_runtime.h>
#include <hip/hip_bf16.h>

#define HID 256
#define EF  64
#define KIN 320      // HID + EF
#define NC  4096
#define NE  65536
#define BSZ 4
#define EPSV 1e-5f

typedef unsigned short ushort_t;
typedef __attribute__((ext_vector_type(8))) short s16x8;
typedef __attribute__((ext_vector_type(16))) float f32x16;

// LDS strides (mod-32-words == 2 -> free 2-way bank alias)
#define EPAD 68      // edge-attr tile row (ushort): 136 B
#define HPAD 260     // bf16 tile row (ushort): 520 B
#define UPAD 520     // node LDS pool row: 1040 B
#define HSF  260     // node h (fp32) stride
#define HOFF 8320    // node H-tile offset in ushorts (16,640 B; ≡0 mod 128B banks)

// round-to-nearest-even fp32 -> bf16 (as ushort bits)
__device__ __forceinline__ ushort_t bf16_rne(float f) {
    unsigned u = __float_as_uint(f);
    return (ushort_t)((u + 0x7fffu + ((u >> 16) & 1u)) >> 16);
}
__device__ __forceinline__ float bf16_to_f(ushort_t u) {
    return __uint_as_float(((unsigned)u) << 16);
}
// packed RNE pair conversion -> v_cvt_pk_bf16_f32 (same bits as bf16_rne pair)
__device__ __forceinline__ unsigned pk_bf16(float a, float b) {
    __hip_bfloat162 h = __float22bfloat162_rn(make_float2(a, b));
    return *reinterpret_cast<unsigned*>(&h);
}
// truncating hi/lo split (pair sums to ~fp32 precision) — for weights (B operand)
__device__ __forceinline__ void split_bf16(float v, ushort_t& h, ushort_t& l) {
    unsigned u = __float_as_uint(v);
    h = (ushort_t)(u >> 16);
    float hf = __uint_as_float(u & 0xffff0000u);
    l = (ushort_t)(__float_as_uint(v - hf) >> 16);
}

// Pack weights into 32x32x16 MFMA B-fragment order, hi/lo bf16.
// frag idx = (t*8 + nt)*64 + lane; elem j: W[t*16 + (lane>>5)*8 + j][nt*32 + (lane&31)]
__device__ __forceinline__ void pack_one(const float* W, int idx,
                                         ushort_t* hi, ushort_t* lo) {
    int l = idx & 63;
    int tn = idx >> 6;
    int nt = tn & 7, t = tn >> 3;
    int k0 = t * 16 + (l >> 5) * 8;
    int col = nt * 32 + (l & 31);
    #pragma unroll
    for (int j = 0; j < 8; ++j) {
        float v = W[(size_t)(k0 + j) * 256 + col];
        ushort_t h, lw;
        split_bf16(v, h, lw);
        hi[(size_t)idx * 8 + j] = h;
        lo[(size_t)idx * 8 + j] = lw;
    }
}

#define FR1 10240    // (320/16)*8*64   mW1 full
#define FR2 8192     // (256/16)*8*64   one 256x256
#define PACK1B 104   // (FR1 + 2*FR2)/256 : mW1, uW1a, uW2
#define FUSEB 256    // W2u rows
#define HISTB 1024   // hist blocks (256 thr each)

// prep: [0,104) pack mW1/uW1a/uW2; [104,360) fuse W2u = mW2 @ uW1b;
// [360] bias2u; [361,1385) hist (counts pre-zeroed by memset)
__global__ __launch_bounds__(256)
void prep_kernel(const float* __restrict__ mW1, const float* __restrict__ uW1,
                 const float* __restrict__ uW2, const float* __restrict__ mW2,
                 const float* __restrict__ ub1, const float* __restrict__ mb2,
                 ushort_t* __restrict__ w1hi, ushort_t* __restrict__ w1lo,
                 ushort_t* __restrict__ u1hi, ushort_t* __restrict__ u1lo,
                 ushort_t* __restrict__ u2hi, ushort_t* __restrict__ u2lo,
                 float* __restrict__ W2u, float* __restrict__ bias2u,
                 const int* __restrict__ eidx, float* __restrict__ counts) {
    int bid = blockIdx.x;
    if (bid < PACK1B) {
        int idx = bid * 256 + threadIdx.x;
        if (idx < FR1) { pack_one(mW1, idx, w1hi, w1lo); return; }
        idx -= FR1;
        if (idx < FR2) { pack_one(uW1, idx, u1hi, u1lo); return; }
        idx -= FR2;
        pack_one(uW2, idx, u2hi, u2lo);
        return;
    }
    bid -= PACK1B;
    if (bid < FUSEB) {               // W2u[k][n] = sum_m mW2[k][m] * uW1[256+m][n]
        int k = bid, n = threadIdx.x;
        const float* wrow = mW2 + (size_t)k * 256;
        float acc = 0.f;
        #pragma unroll 8
        for (int m = 0; m < 256; ++m)
            acc = fmaf(wrow[m], uW1[(size_t)(256 + m) * 256 + n], acc);
        W2u[(size_t)k * 256 + n] = acc;
        return;
    }
    bid -= FUSEB;
    if (bid == 0) {                  // bias2u[n] = ub1[n] + sum_m mb2[m]*uW1[256+m][n]
        int n = threadIdx.x;
        float acc = ub1[n];
        #pragma unroll 8
        for (int m = 0; m < 256; ++m)
            acc = fmaf(mb2[m], uW1[(size_t)(256 + m) * 256 + n], acc);
        bias2u[n] = acc;
        return;
    }
    bid -= 1;
    // ---- hist ----
    int i = bid * 256 + threadIdx.x;             // < BSZ*NE
    int b = i >> 16;
    int2 v = ((const int2*)eidx)[i];
    int d = min(max(v.y, 0), NC - 1);
    atomicAdd(&counts[b * NC + d], 1.0f);
}

// ======================= pre ∥ scansc ∥ W2u-pack (one dispatch) =======================
// blocks [0,512): pre GEMM; [512,1024): scan+scatter; [1024,1040): pack W2u
__global__ __launch_bounds__(512, 4)
void hp_kernel(const int* __restrict__ eidx, const float* __restrict__ counts,
               int* __restrict__ filled, int* __restrict__ sorted,
               const float* __restrict__ cell_x,
               const ushort_t* __restrict__ w1hi, const ushort_t* __restrict__ w1lo,
               const ushort_t* __restrict__ u1hi, const ushort_t* __restrict__ u1lo,
               float* __restrict__ Pe, ushort_t* __restrict__ Pn,
               const float* __restrict__ W2u,
               ushort_t* __restrict__ w2uhi, ushort_t* __restrict__ w2ulo) {
    __shared__ ushort_t Us[32 * HPAD];           // 16,640 B; scansc aliases as int[4096]
    __shared__ int wsum[8];

    if (blockIdx.x >= 1024) {        // ---- pack W2u ----
        int idx = (blockIdx.x - 1024) * 512 + threadIdx.x;   // < FR2
        pack_one(W2u, idx, w2uhi, w2ulo);
        return;
    }

    if (blockIdx.x >= 512) {         // ---- scan-in-block + scatter ----
        int* woffL = (int*)Us;       // 16,384 B <= 16,640 B
        const int t = threadIdx.x;
        const int sbid = blockIdx.x - 512;
        const int b = sbid >> 7;

        int c[8];
        int ts = 0;
        const int base = b * NC + t * 8;
        #pragma unroll
        for (int j = 0; j < 8; ++j) { c[j] = (int)counts[base + j]; ts += c[j]; }

        int lane = t & 63;
        int x = ts;
        #pragma unroll
        for (int off = 1; off < 64; off <<= 1) {
            int y = __shfl_up(x, off, 64);
            if (lane >= off) x += y;
        }
        if (lane == 63) wsum[t >> 6] = x;
        __syncthreads();
        if (t == 0) {
            int s = 0;
            #pragma unroll
            for (int w = 0; w < 8; ++w) { int tmp = wsum[w]; wsum[w] = s; s += tmp; }
        }
        __syncthreads();
        int run = wsum[t >> 6] + (x - ts);
        #pragma unroll
        for (int j = 0; j < 8; ++j) { woffL[t * 8 + j] = run; run += c[j]; }
        __syncthreads();

        int e = (sbid & 127) * 512 + t;          // edge id within batch
        int2 v = ((const int2*)eidx)[(size_t)b * NE + e];
        int d = min(max(v.y, 0), NC - 1);
        int pos = woffL[d] + atomicAdd(&filled[b * NC + d], 1);
        sorted[(size_t)b * NE + pos] = e;
        return;
    }

    // ---- pre: Pe = cell_x @ mW1[:256,:] (fp32), Pn = cell_x @ uW1[:256,:] (bf16)
    const int tid = threadIdx.x;
    const size_t r0 = (size_t)blockIdx.x * 32;   // global row in [0, B*NC)
    const int wv = tid >> 6, ln = tid & 63;
    const int m32 = ln & 31, half = ln >> 5;
    const int col = wv * 32 + m32;

    const ushort_t* wph = w1hi + ((size_t)wv * 64 + ln) * 8;
    const ushort_t* wpl = w1lo + ((size_t)wv * 64 + ln) * 8;
    const ushort_t* uph = u1hi + ((size_t)wv * 64 + ln) * 8;
    const ushort_t* upl = u1lo + ((size_t)wv * 64 + ln) * 8;
    s16x8 wh = *(const s16x8*)wph, wl = *(const s16x8*)wpl;
    s16x8 uh = *(const s16x8*)uph, ul = *(const s16x8*)upl;

    // stage cell_x rows as RNE bf16
    {
        const int row = tid >> 4, c8 = tid & 15;
        const float4* crow = (const float4*)(cell_x + (r0 + row) * HID);
        #pragma unroll
        for (int i = 0; i < 4; ++i) {
            int c = c8 + i * 16;
            float4 v = crow[c];
            *(uint2*)&Us[row * HPAD + c * 4] =
                make_uint2(pk_bf16(v.x, v.y), pk_bf16(v.z, v.w));
        }
    }
    __syncthreads();

    f32x16 aw, au;
    #pragma unroll
    for (int r = 0; r < 16; ++r) { aw[r] = 0.f; au[r] = 0.f; }

    #pragma unroll 2
    for (int t = 0; t < 16; ++t) {
        int tn = (t + 1 < 16) ? t + 1 : 15;
        s16x8 whn = *(const s16x8*)(wph + (size_t)tn * 4096);
        s16x8 wln = *(const s16x8*)(wpl + (size_t)tn * 4096);
        s16x8 uhn = *(const s16x8*)(uph + (size_t)tn * 4096);
        s16x8 uln = *(const s16x8*)(upl + (size_t)tn * 4096);
        s16x8 a = *(const s16x8*)&Us[m32 * HPAD + t * 16 + half * 8];
        aw = __builtin_amdgcn_mfma_f32_32x32x16_bf16(a, wh, aw, 0, 0, 0);
        aw = __builtin_amdgcn_mfma_f32_32x32x16_bf16(a, wl, aw, 0, 0, 0);
        au = __builtin_amdgcn_mfma_f32_32x32x16_bf16(a, uh, au, 0, 0, 0);
        au = __builtin_amdgcn_mfma_f32_32x32x16_bf16(a, ul, au, 0, 0, 0);
        wh = whn; wl = wln; uh = uhn; ul = uln;
    }

    #pragma unroll
    for (int r = 0; r < 16; ++r) {
        int row = (r & 3) + 8 * (r >> 2) + 4 * half;
        Pe[(r0 + row) * 256 + col] = aw[r];
        Pn[(r0 + row) * 256 + col] = bf16_rne(au[r]);
    }
}

// 64 sorted edges/block, 512 threads = 8 waves. Single barrier; ids in registers,
// cross-lane via shfl. relu(Pe[src] + eattr@W1b + mb1) -> suffix-difference
// segmented reduce over sorted dst runs -> aggf (plain store for block-exclusive
// runs, fp32 atomics for window-boundary runs). XCD-swizzled blockIdx.
__global__ __launch_bounds__(512, 4)
void edge_kernel(const float* __restrict__ Pe,
                 const int*   __restrict__ eidx,
                 const int*   __restrict__ sorted,
                 const float* __restrict__ eattr,
                 const ushort_t* __restrict__ w1hi, const ushort_t* __restrict__ w1lo,
                 const float* __restrict__ b1,
                 float* __restrict__ aggf) {
    __shared__ ushort_t Xs[64 * EPAD];   // 8,704 B

    const int tid = threadIdx.x;
    // XCD-aware swizzle: grid 4096, 8 XCDs -> each XCD gets a contiguous 512-block
    // chunk (same batch, contiguous dst range) for Pe/aggf L2 locality.
    const int swz = (blockIdx.x & 7) * 512 + (blockIdx.x >> 3);
    const int b   = swz >> 10;                   // 1024 blocks per batch
    const int e0  = (swz & 1023) * 64;
    const int wv = tid >> 6, ln = tid & 63;
    const int m32 = ln & 31, half = ln >> 5;
    const int col = wv * 32 + m32;

    // ---- per-lane edge ids (each wave redundantly; L1/L2 broadcast) ----
    int eid = sorted[(size_t)b * NE + e0 + ln];
    int2 ev = ((const int2*)eidx)[(size_t)b * NE + eid];
    int src = min(max(ev.x, 0), NC - 1);
    int dst = min(max(ev.y, 0), NC - 1);

    // ---- W1b (eattr part, packed t=16..19) B fragments ----
    const ushort_t* ph = w1hi + ((size_t)(16 * 8 + wv) * 64 + ln) * 8;
    const ushort_t* pl = w1lo + ((size_t)(16 * 8 + wv) * 64 + ln) * 8;
    s16x8 bh0 = *(const s16x8*)ph;
    s16x8 bl0 = *(const s16x8*)pl;
    s16x8 bh1 = *(const s16x8*)(ph + 4096);
    s16x8 bl1 = *(const s16x8*)(pl + 4096);
    s16x8 bh2 = *(const s16x8*)(ph + 8192);
    s16x8 bl2 = *(const s16x8*)(pl + 8192);
    s16x8 bh3 = *(const s16x8*)(ph + 12288);
    s16x8 bl3 = *(const s16x8*)(pl + 12288);

    // ---- Pe gather (rows via shfl; 32 independent loads in flight) ----
    float t0[16], t1[16];
    {
        const float* pb = Pe + (size_t)b * NC * 256 + col;
        #pragma unroll
        for (int r = 0; r < 16; ++r) {
            int rw = (r & 3) + 8 * (r >> 2) + 4 * half;
            t0[r] = pb[(size_t)__shfl(src, rw, 64) * 256];
            t1[r] = pb[(size_t)__shfl(src, rw + 32, 64) * 256];
        }
    }

    // ---- stage eattr (64x64, gathered rows) as RNE bf16 ----
    {
        const int rowE = tid >> 3, c8 = tid & 7;
        int eidr = __shfl(eid, rowE, 64);
        const float4* arow = (const float4*)(eattr + ((size_t)b * NE + eidr) * EF);
        #pragma unroll
        for (int i = 0; i < 2; ++i) {
            int c = c8 + i * 8;
            float4 v = arow[c];
            *(uint2*)&Xs[rowE * EPAD + c * 4] =
                make_uint2(pk_bf16(v.x, v.y), pk_bf16(v.z, v.w));
        }
    }
    __syncthreads();   // the only barrier: eattr tile ready

    // ---- GEMM1: h1 = eattr @ W1b + b1, K=64 ----
    f32x16 A0, A1;
    {
        float bias = b1[col];
        #pragma unroll
        for (int r = 0; r < 16; ++r) { A0[r] = bias; A1[r] = bias; }
    }
    {
        int ao = m32 * EPAD + half * 8;
        s16x8 a0, a1;
        a0 = *(const s16x8*)&Xs[ao];      a1 = *(const s16x8*)&Xs[ao + 32 * EPAD];
        A0 = __builtin_amdgcn_mfma_f32_32x32x16_bf16(a0, bh0, A0, 0, 0, 0);
        A0 = __builtin_amdgcn_mfma_f32_32x32x16_bf16(a0, bl0, A0, 0, 0, 0);
        A1 = __builtin_amdgcn_mfma_f32_32x32x16_bf16(a1, bh0, A1, 0, 0, 0);
        A1 = __builtin_amdgcn_mfma_f32_32x32x16_bf16(a1, bl0, A1, 0, 0, 0);
        a0 = *(const s16x8*)&Xs[ao + 16]; a1 = *(const s16x8*)&Xs[ao + 16 + 32 * EPAD];
        A0 = __builtin_amdgcn_mfma_f32_32x32x16_bf16(a0, bh1, A0, 0, 0, 0);
        A0 = __builtin_amdgcn_mfma_f32_32x32x16_bf16(a0, bl1, A0, 0, 0, 0);
        A1 = __builtin_amdgcn_mfma_f32_32x32x16_bf16(a1, bh1, A1, 0, 0, 0);
        A1 = __builtin_amdgcn_mfma_f32_32x32x16_bf16(a1, bl1, A1, 0, 0, 0);
        a0 = *(const s16x8*)&Xs[ao + 32]; a1 = *(const s16x8*)&Xs[ao + 32 + 32 * EPAD];
        A0 = __builtin_amdgcn_mfma_f32_32x32x16_bf16(a0, bh2, A0, 0, 0, 0);
        A0 = __builtin_amdgcn_mfma_f32_32x32x16_bf16(a0, bl2, A0, 0, 0, 0);
        A1 = __builtin_amdgcn_mfma_f32_32x32x16_bf16(a1, bh2, A1, 0, 0, 0);
        A1 = __builtin_amdgcn_mfma_f32_32x32x16_bf16(a1, bl2, A1, 0, 0, 0);
        a0 = *(const s16x8*)&Xs[ao + 48]; a1 = *(const s16x8*)&Xs[ao + 48 + 32 * EPAD];
        A0 = __builtin_amdgcn_mfma_f32_32x32x16_bf16(a0, bh3, A0, 0, 0, 0);
        A0 = __builtin_amdgcn_mfma_f32_32x32x16_bf16(a0, bl3, A0, 0, 0, 0);
        A1 = __builtin_amdgcn_mfma_f32_32x32x16_bf16(a1, bh3, A1, 0, 0, 0);
        A1 = __builtin_amdgcn_mfma_f32_32x32x16_bf16(a1, bl3, A1, 0, 0, 0);
    }

    // ---- fold Pe[src] + relu ----
    #pragma unroll
    for (int r = 0; r < 16; ++r) {
        A0[r] = fmaxf(A0[r] + t0[r], 0.f);
        A1[r] = fmaxf(A1[r] + t1[r], 0.f);
    }

    // ---- suffix-difference segmented reduce over sorted dst runs ----
    // run [lo,hi) sum = S(lo) - S(hi); S(lo_k) = S(hi_{k-1}).
    // Runs with lo>0 && hi<32 are globally complete (sorted) -> plain store.
    {
        const int l31 = ln & 31;
        // rows 0..31 (A0)
        int dl = __shfl(dst, l31, 64);
        int dp = __shfl(dst, (l31 == 0) ? 0 : l31 - 1, 64);
        if (l31 == 0) dp = ~dl;
        unsigned m = (unsigned)__ballot(dl != dp);
        unsigned rem = m & ~1u;
        float prev = (((A0[0] + A0[1]) + (A0[2] + A0[3])) + ((A0[4] + A0[5]) + (A0[6] + A0[7])))
                   + (((A0[8] + A0[9]) + (A0[10] + A0[11])) + ((A0[12] + A0[13]) + (A0[14] + A0[15])));
        int lo = 0;
        while (lo < 32) {
            int hi = rem ? (int)__builtin_ctz(rem) : 32;
            rem &= rem - 1;
            int d = __shfl(dl, lo, 64);
            float shi = 0.f;
            if (hi < 32) {
                #pragma unroll
                for (int r = 0; r < 16; ++r) {
                    int row = (r & 3) + 8 * (r >> 2) + 4 * half;
                    shi += (row >= hi) ? A0[r] : 0.f;
                }
            }
            float s = prev - shi;
            prev = shi;
            s += __shfl_xor(s, 32, 64);
            if (ln < 32) {
                float* addr = &aggf[((size_t)b * NC + d) * HID + col];
                if (lo > 0 && hi < 32) *addr = s;     // block-exclusive run
                else atomicAdd(addr, s);              // window-boundary run
            }
            lo = hi;
        }
        // rows 32..63 (A1)
        dl = __shfl(dst, 32 + l31, 64);
        dp = __shfl(dst, 32 + ((l31 == 0) ? 0 : l31 - 1), 64);
        if (l31 == 0) dp = ~dl;
        m = (unsigned)__ballot(dl != dp);
        rem = m & ~1u;
        prev = (((A1[0] + A1[1]) + (A1[2] + A1[3])) + ((A1[4] + A1[5]) + (A1[6] + A1[7])))
             + (((A1[8] + A1[9]) + (A1[10] + A1[11])) + ((A1[12] + A1[13]) + (A1[14] + A1[15])));
        lo = 0;
        while (lo < 32) {
            int hi = rem ? (int)__builtin_ctz(rem) : 32;
            rem &= rem - 1;
            int d = __shfl(dl, lo, 64);
            float shi = 0.f;
            if (hi < 32) {
                #pragma unroll
                for (int r = 0; r < 16; ++r) {
                    int row = (r & 3) + 8 * (r >> 2) + 4 * half;
                    shi += (row >= hi) ? A1[r] : 0.f;
                }
            }
            float s = prev - shi;
            prev = shi;
            s += __shfl_xor(s, 32, 64);
            if (ln < 32) {
                float* addr = &aggf[((size_t)b * NC + d) * HID + col];
                if (lo > 0 && hi < 32) *addr = s;     // block-exclusive run
                else atomicAdd(addr, s);              // window-boundary run
            }
            lo = hi;
        }
    }
}

// 32 nodes/block, 512 threads = 8 waves; wave wv owns n-tile wv, 1 m-tile.
// H tile lives in the second LDS region -> no barrier between GEMM1 and H-store.
__global__ __launch_bounds__(512, 4)
void node_kernel(const float* __restrict__ cell_x,
                 const float* __restrict__ aggf,
                 const float* __restrict__ counts,
                 const ushort_t* __restrict__ Pn,
                 const ushort_t* __restrict__ w2uhi, const ushort_t* __restrict__ w2ulo,
                 const float* __restrict__ bias2u,
                 const ushort_t* __restrict__ u2hi, const ushort_t* __restrict__ u2lo,
                 const float* __restrict__ b2,
                 const float* __restrict__ gamma, const float* __restrict__ beta,
                 float* __restrict__ out) {
    __shared__ ushort_t Us[32 * UPAD];   // [0,HOFF): agg bf16; [HOFF,2*HOFF): H bf16; hs fp32 overlay
    float* hs = (float*)Us;

    const int tid = threadIdx.x;
    const int b   = blockIdx.x >> 7;             // 128 blocks per batch
    const int r0  = (blockIdx.x & 127) * 32;
    const int wv = tid >> 6, ln = tid & 63;
    const int m32 = ln & 31, half = ln >> 5;
    const int col = wv * 32 + m32;

    // hoisted W2u (fused mW2@uW1b) B-prefetch
    const ushort_t* b1ph = w2uhi + ((size_t)wv * 64 + ln) * 8;
    const ushort_t* b1pl = w2ulo + ((size_t)wv * 64 + ln) * 8;
    s16x8 bhi = *(const s16x8*)b1ph;
    s16x8 blo = *(const s16x8*)b1pl;

    // ---- issue Pn gather early (consumed after GEMM1) ----
    ushort_t pnt[16];
    {
        const ushort_t* pb = Pn + ((size_t)b * NC + r0) * 256 + col;
        #pragma unroll
        for (int r = 0; r < 16; ++r) {
            int row = (r & 3) + 8 * (r >> 2) + 4 * half;
            pnt[r] = pb[(size_t)row * 256];
        }
    }

    // ---- stage aggH*inv (fp32 -> RNE bf16), 32 x 256; inv loaded directly ----
    {
        const int row = tid >> 4, c8 = tid & 15;
        float inv = 1.0f / fmaxf(counts[b * NC + r0 + row], 1.0f);
        const float4* grow = (const float4*)(aggf + ((size_t)b * NC + r0 + row) * HID);
        #pragma unroll
        for (int i = 0; i < 4; ++i) {
            int c = c8 + i * 16;
            float4 g = grow[c];
            *(uint2*)&Us[row * HPAD + c * 4] =
                make_uint2(pk_bf16(g.x * inv, g.y * inv), pk_bf16(g.z * inv, g.w * inv));
        }
    }
    __syncthreads();   // barrier 1: agg tile ready

    // ---- GEMM1: acc = (aggH/deg) @ W2u + bias2u, K=256 ----
    f32x16 acc;
    {
        float bias = bias2u[col];
        #pragma unroll
        for (int r = 0; r < 16; ++r) acc[r] = bias;
    }
    #pragma unroll 2
    for (int t = 0; t < 16; ++t) {
        int tn1 = (t + 1 < 16) ? t + 1 : 15;
        s16x8 bhin = *(const s16x8*)(b1ph + (size_t)tn1 * 4096);
        s16x8 blon = *(const s16x8*)(b1pl + (size_t)tn1 * 4096);
        s16x8 a = *(const s16x8*)&Us[m32 * HPAD + t * 16 + half * 8];
        acc = __builtin_amdgcn_mfma_f32_32x32x16_bf16(a, bhi, acc, 0, 0, 0);
        acc = __builtin_amdgcn_mfma_f32_32x32x16_bf16(a, blo, acc, 0, 0, 0);
        bhi = bhin; blo = blon;
    }

    // ---- add Pn (cell_x @ uW1a half) ----
    #pragma unroll
    for (int r = 0; r < 16; ++r) acc[r] += bf16_to_f(pnt[r]);

    // hoisted uW2 B-prefetch
    const ushort_t* b2ph = u2hi + ((size_t)wv * 64 + ln) * 8;
    const ushort_t* b2pl = u2lo + ((size_t)wv * 64 + ln) * 8;
    bhi = *(const s16x8*)b2ph;
    blo = *(const s16x8*)b2pl;

    // ---- relu + store H to region 2 (no barrier needed before store) ----
    #pragma unroll
    for (int r = 0; r < 16; ++r) {
        int row = (r & 3) + 8 * (r >> 2) + 4 * half;
        Us[HOFF + row * HPAD + col] = bf16_rne(fmaxf(acc[r], 0.f));
    }
    __syncthreads();   // barrier 2: H ready

    // ---- issue residual cell_x loads early (consumed after GEMM2) ----
    float cxt[16];
    #pragma unroll
    for (int r = 0; r < 16; ++r) {
        int row = (r & 3) + 8 * (r >> 2) + 4 * half;
        cxt[r] = cell_x[((size_t)b * NC + r0 + row) * HID + col];
    }

    // ---- GEMM2: o = hidden @ uW2 + ub2, K=256 ----
    f32x16 c2;
    {
        float bias = b2[col];
        #pragma unroll
        for (int r = 0; r < 16; ++r) c2[r] = bias;
    }
    #pragma unroll 2
    for (int t = 0; t < 16; ++t) {
        int tn1 = (t + 1 < 16) ? t + 1 : 15;
        s16x8 bhin = *(const s16x8*)(b2ph + (size_t)tn1 * 4096);
        s16x8 blon = *(const s16x8*)(b2pl + (size_t)tn1 * 4096);
        s16x8 a = *(const s16x8*)&Us[HOFF + m32 * HPAD + t * 16 + half * 8];
        c2 = __builtin_amdgcn_mfma_f32_32x32x16_bf16(a, bhi, c2, 0, 0, 0);
        c2 = __builtin_amdgcn_mfma_f32_32x32x16_bf16(a, blo, c2, 0, 0, 0);
        bhi = bhin; blo = blon;
    }
    __syncthreads();   // barrier 3: H dead; hs overlay may overwrite whole pool

    // ---- residual: h = cell_x + o ----
    #pragma unroll
    for (int r = 0; r < 16; ++r) {
        int row = (r & 3) + 8 * (r >> 2) + 4 * half;
        hs[row * HSF + col] = c2[r] + cxt[r];
    }
    __syncthreads();   // barrier 4: hs ready

    // ---- LayerNorm per row: wave wv handles rows wv*4..+3 ----
    #pragma unroll
    for (int i = 0; i < 4; ++i) {
        int r = wv * 4 + i;
        float v[4];
        float s = 0.f, q = 0.f;
        #pragma unroll
        for (int j = 0; j < 4; ++j) {
            v[j] = hs[r * HSF + ln + 64 * j];
            s += v[j];
            q = fmaf(v[j], v[j], q);
        }
        #pragma unroll
        for (int off = 32; off > 0; off >>= 1) {
            s += __shfl_xor(s, off, 64);
            q += __shfl_xor(q, off, 64);
        }
        float mu = s * (1.0f / HID);
        float var = q * (1.0f / HID) - mu * mu;
        float rs = rsqrtf(var + EPSV);
        float* orow = out + ((size_t)b * NC + r0 + r) * HID;
        #pragma unroll
        for (int j = 0; j < 4; ++j) {
            int c = ln + 64 * j;
            orow[c] = (v[j] - mu) * rs * gamma[c] + beta[c];
        }
    }
}

extern "C" void kernel_launch(void* const* d_in, const int* in_sizes, int n_in,
                              void* d_out, int out_size, void* d_ws, size_t ws_size,
                              hipStream_t stream) {
    const float* cell_x = (const float*)d_in[0];
    const int*   eidx   = (const int*)d_in[1];
    const float* eattr  = (const float*)d_in[2];
    const float* mW1    = (const float*)d_in[3];
    const float* mb1    = (const float*)d_in[4];
    const float* mW2    = (const float*)d_in[5];
    const float* mb2    = (const float*)d_in[6];
    const float* uW1    = (const float*)d_in[7];
    const float* ub1    = (const float*)d_in[8];
    const float* uW2    = (const float*)d_in[9];
    const float* ub2    = (const float*)d_in[10];
    const float* gamma  = (const float*)d_in[11];
    const float* beta   = (const float*)d_in[12];
    float* out = (float*)d_out;

    // workspace layout (~42.4 MB; proven fits)
    float* aggf   = (float*)d_ws;                        // [B,NC,HID] fp32, 16 MB (memset)
    float* counts = aggf + (size_t)BSZ * NC * HID;       // [B,NC] fp32 (memset)
    int*   filled = (int*)(counts + BSZ * NC);           // [B,NC] int (memset)
    int*   sorted = filled + BSZ * NC;                   // [B,NE] int, 1 MB
    ushort_t* w1hi = (ushort_t*)(sorted + (size_t)BSZ * NE);   // mW1 pack (320 rows)
    ushort_t* w1lo = w1hi + KIN * HID;
    ushort_t* u1hi = w1lo + KIN * HID;                   // uW1[:256] pack
    ushort_t* u1lo = u1hi + HID * HID;
    ushort_t* u2hi = u1lo + HID * HID;                   // uW2 pack
    ushort_t* u2lo = u2hi + HID * HID;
    ushort_t* w2uhi = u2lo + HID * HID;                  // fused W2u pack
    ushort_t* w2ulo = w2uhi + HID * HID;
    float*    W2u   = (float*)(w2ulo + HID * HID);       // raw fused weight, 256 KB
    float*    bias2u = W2u + HID * HID;                  // fused bias, 1 KB
    float*    Pe   = bias2u + HID;                       // [B*NC,256] fp32, 16 MB
    ushort_t* Pn   = (ushort_t*)(Pe + (size_t)BSZ * NC * 256); // [B*NC,256] bf16, 8 MB

    // zero aggf + counts + filled (contiguous at d_ws start) via async memset
    size_t zbytes = (size_t)BSZ * NC * HID * 4 + (size_t)BSZ * NC * 4 + (size_t)BSZ * NC * 4;
    hipMemsetAsync(d_ws, 0, zbytes, stream);

    prep_kernel<<<PACK1B + FUSEB + 1 + HISTB, 256, 0, stream>>>(
        mW1, uW1, uW2, mW2, ub1, mb2,
        w1hi, w1lo, u1hi, u1lo, u2hi, u2lo, W2u, bias2u, eidx, counts);
    hp_kernel<<<1040, 512, 0, stream>>>(eidx, counts, filled, sorted, cell_x,
                                        w1hi, w1lo, u1hi, u1lo, Pe, Pn,
                                        W2u, w2uhi, w2ulo);
    edge_kernel<<<BSZ * NE / 64, 512, 0, stream>>>(Pe, eidx, sorted, eattr,
                                                   w1hi, w1lo, mb1, aggf);
    node_kernel<<<BSZ * NC / 32, 512, 0, stream>>>(cell_x, aggf, counts, Pn,
                                                   w2uhi, w2ulo, bias2u,
                                                   u2hi, u2lo, ub2,
                                                   gamma, beta, out);
}

// Round 13
// 246.309 us; speedup vs baseline: 1.0161x; 1.0161x over previous
//
#include <hip/hip_runtime.h>
#include <hip/hip_bf16.h>

#define HID 256
#define EF  64
#define KIN 320      // HID + EF
#define NC  4096
#define NE  65536
#define BSZ 4
#define EPSV 1e-5f

typedef unsigned short ushort_t;
typedef __attribute__((ext_vector_type(8))) short s16x8;
typedef __attribute__((ext_vector_type(16))) float f32x16;

// LDS strides (mod-32-words == 2 -> free 2-way bank alias)
#define EPAD 68      // edge-attr tile row (ushort): 136 B
#define HPAD 260     // bf16 tile row (ushort): 520 B
#define UPAD 520     // node LDS pool row: 1040 B
#define HSF  260     // node h (fp32) stride
#define HOFF 8320    // node H-tile offset in ushorts (16,640 B)

// round-to-nearest-even fp32 -> bf16 (as ushort bits)
__device__ __forceinline__ ushort_t bf16_rne(float f) {
    unsigned u = __float_as_uint(f);
    return (ushort_t)((u + 0x7fffu + ((u >> 16) & 1u)) >> 16);
}
__device__ __forceinline__ float bf16_to_f(ushort_t u) {
    return __uint_as_float(((unsigned)u) << 16);
}
// packed RNE pair conversion -> v_cvt_pk_bf16_f32 (same bits as bf16_rne pair)
__device__ __forceinline__ unsigned pk_bf16(float a, float b) {
    __hip_bfloat162 h = __float22bfloat162_rn(make_float2(a, b));
    return *reinterpret_cast<unsigned*>(&h);
}
// truncating hi/lo split (pair sums to ~fp32 precision) — for weights (B operand)
__device__ __forceinline__ void split_bf16(float v, ushort_t& h, ushort_t& l) {
    unsigned u = __float_as_uint(v);
    h = (ushort_t)(u >> 16);
    float hf = __uint_as_float(u & 0xffff0000u);
    l = (ushort_t)(__float_as_uint(v - hf) >> 16);
}

// Pack weights into 32x32x16 MFMA B-fragment order, hi/lo bf16.
__device__ __forceinline__ void pack_one(const float* W, int idx,
                                         ushort_t* hi, ushort_t* lo) {
    int l = idx & 63;
    int tn = idx >> 6;
    int nt = tn & 7, t = tn >> 3;
    int k0 = t * 16 + (l >> 5) * 8;
    int col = nt * 32 + (l & 31);
    #pragma unroll
    for (int j = 0; j < 8; ++j) {
        float v = W[(size_t)(k0 + j) * 256 + col];
        ushort_t h, lw;
        split_bf16(v, h, lw);
        hi[(size_t)idx * 8 + j] = h;
        lo[(size_t)idx * 8 + j] = lw;
    }
}

#define FR1 10240    // (320/16)*8*64   mW1 full
#define FR2 8192     // (256/16)*8*64   one 256x256
#define PACK1B 104   // (FR1 + 2*FR2)/256 : mW1, uW1a, uW2
#define FUSEB 256    // W2u rows
#define HISTB 1024   // hist blocks (256 thr each)

// prep: [0,104) pack mW1/uW1a/uW2; [104,360) fuse W2u = mW2 @ uW1b;
// [360] bias2u; [361,1385) hist (counts pre-zeroed by memset)
__global__ __launch_bounds__(256)
void prep_kernel(const float* __restrict__ mW1, const float* __restrict__ uW1,
                 const float* __restrict__ uW2, const float* __restrict__ mW2,
                 const float* __restrict__ ub1, const float* __restrict__ mb2,
                 ushort_t* __restrict__ w1hi, ushort_t* __restrict__ w1lo,
                 ushort_t* __restrict__ u1hi, ushort_t* __restrict__ u1lo,
                 ushort_t* __restrict__ u2hi, ushort_t* __restrict__ u2lo,
                 float* __restrict__ W2u, float* __restrict__ bias2u,
                 const int* __restrict__ eidx, float* __restrict__ counts) {
    int bid = blockIdx.x;
    if (bid < PACK1B) {
        int idx = bid * 256 + threadIdx.x;
        if (idx < FR1) { pack_one(mW1, idx, w1hi, w1lo); return; }
        idx -= FR1;
        if (idx < FR2) { pack_one(uW1, idx, u1hi, u1lo); return; }
        idx -= FR2;
        pack_one(uW2, idx, u2hi, u2lo);
        return;
    }
    bid -= PACK1B;
    if (bid < FUSEB) {               // W2u[k][n] = sum_m mW2[k][m] * uW1[256+m][n]
        int k = bid, n = threadIdx.x;
        const float* wrow = mW2 + (size_t)k * 256;
        float acc = 0.f;
        #pragma unroll 8
        for (int m = 0; m < 256; ++m)
            acc = fmaf(wrow[m], uW1[(size_t)(256 + m) * 256 + n], acc);
        W2u[(size_t)k * 256 + n] = acc;
        return;
    }
    bid -= FUSEB;
    if (bid == 0) {                  // bias2u[n] = ub1[n] + sum_m mb2[m]*uW1[256+m][n]
        int n = threadIdx.x;
        float acc = ub1[n];
        #pragma unroll 8
        for (int m = 0; m < 256; ++m)
            acc = fmaf(mb2[m], uW1[(size_t)(256 + m) * 256 + n], acc);
        bias2u[n] = acc;
        return;
    }
    bid -= 1;
    // ---- hist ----
    int i = bid * 256 + threadIdx.x;             // < BSZ*NE
    int b = i >> 16;
    int2 v = ((const int2*)eidx)[i];
    int d = min(max(v.y, 0), NC - 1);
    atomicAdd(&counts[b * NC + d], 1.0f);
}

// ======================= pre ∥ scansc ∥ W2u-pack (one dispatch) =======================
// blocks [0,512): pre GEMM; [512,1024): scan+scatter; [1024,1040): pack W2u
__global__ __launch_bounds__(512, 4)
void hp_kernel(const int* __restrict__ eidx, const float* __restrict__ counts,
               int* __restrict__ filled, int* __restrict__ sorted, int payload,
               const float* __restrict__ cell_x,
               const ushort_t* __restrict__ w1hi, const ushort_t* __restrict__ w1lo,
               const ushort_t* __restrict__ u1hi, const ushort_t* __restrict__ u1lo,
               float* __restrict__ Pe, ushort_t* __restrict__ Pn,
               const float* __restrict__ W2u,
               ushort_t* __restrict__ w2uhi, ushort_t* __restrict__ w2ulo) {
    __shared__ ushort_t Us[32 * HPAD];           // 16,640 B; scansc aliases as int[4096]
    __shared__ int wsum[8];

    if (blockIdx.x >= 1024) {        // ---- pack W2u ----
        int idx = (blockIdx.x - 1024) * 512 + threadIdx.x;   // < FR2
        pack_one(W2u, idx, w2uhi, w2ulo);
        return;
    }

    if (blockIdx.x >= 512) {         // ---- scan-in-block + scatter ----
        int* woffL = (int*)Us;       // 16,384 B <= 16,640 B
        const int t = threadIdx.x;
        const int sbid = blockIdx.x - 512;
        const int b = sbid >> 7;

        int c[8];
        int ts = 0;
        const int base = b * NC + t * 8;
        #pragma unroll
        for (int j = 0; j < 8; ++j) { c[j] = (int)counts[base + j]; ts += c[j]; }

        int lane = t & 63;
        int x = ts;
        #pragma unroll
        for (int off = 1; off < 64; off <<= 1) {
            int y = __shfl_up(x, off, 64);
            if (lane >= off) x += y;
        }
        if (lane == 63) wsum[t >> 6] = x;
        __syncthreads();
        if (t == 0) {
            int s = 0;
            #pragma unroll
            for (int w = 0; w < 8; ++w) { int tmp = wsum[w]; wsum[w] = s; s += tmp; }
        }
        __syncthreads();
        int run = wsum[t >> 6] + (x - ts);
        #pragma unroll
        for (int j = 0; j < 8; ++j) { woffL[t * 8 + j] = run; run += c[j]; }
        __syncthreads();

        int e = (sbid & 127) * 512 + t;          // edge id within batch
        int2 v = ((const int2*)eidx)[(size_t)b * NE + e];
        int s = min(max(v.x, 0), NC - 1);
        int d = min(max(v.y, 0), NC - 1);
        int pos = woffL[d] + atomicAdd(&filled[b * NC + d], 1);
        if (payload) {
            ((int2*)sorted)[(size_t)b * NE + pos] = make_int2(e, s | (d << 12));
        } else {
            sorted[(size_t)b * NE + pos] = e;
        }
        return;
    }

    // ---- pre: Pe = cell_x @ mW1[:256,:] (fp32), Pn = cell_x @ uW1[:256,:] (bf16)
    const int tid = threadIdx.x;
    const size_t r0 = (size_t)blockIdx.x * 32;   // global row in [0, B*NC)
    const int wv = tid >> 6, ln = tid & 63;
    const int m32 = ln & 31, half = ln >> 5;
    const int col = wv * 32 + m32;

    const ushort_t* wph = w1hi + ((size_t)wv * 64 + ln) * 8;
    const ushort_t* wpl = w1lo + ((size_t)wv * 64 + ln) * 8;
    const ushort_t* uph = u1hi + ((size_t)wv * 64 + ln) * 8;
    const ushort_t* upl = u1lo + ((size_t)wv * 64 + ln) * 8;
    s16x8 wh = *(const s16x8*)wph, wl = *(const s16x8*)wpl;
    s16x8 uh = *(const s16x8*)uph, ul = *(const s16x8*)upl;

    // stage cell_x rows as RNE bf16
    {
        const int row = tid >> 4, c8 = tid & 15;
        const float4* crow = (const float4*)(cell_x + (r0 + row) * HID);
        #pragma unroll
        for (int i = 0; i < 4; ++i) {
            int c = c8 + i * 16;
            float4 v = crow[c];
            *(uint2*)&Us[row * HPAD + c * 4] =
                make_uint2(pk_bf16(v.x, v.y), pk_bf16(v.z, v.w));
        }
    }
    __syncthreads();

    f32x16 aw, au;
    #pragma unroll
    for (int r = 0; r < 16; ++r) { aw[r] = 0.f; au[r] = 0.f; }

    #pragma unroll 2
    for (int t = 0; t < 16; ++t) {
        int tn = (t + 1 < 16) ? t + 1 : 15;
        s16x8 whn = *(const s16x8*)(wph + (size_t)tn * 4096);
        s16x8 wln = *(const s16x8*)(wpl + (size_t)tn * 4096);
        s16x8 uhn = *(const s16x8*)(uph + (size_t)tn * 4096);
        s16x8 uln = *(const s16x8*)(upl + (size_t)tn * 4096);
        s16x8 a = *(const s16x8*)&Us[m32 * HPAD + t * 16 + half * 8];
        aw = __builtin_amdgcn_mfma_f32_32x32x16_bf16(a, wh, aw, 0, 0, 0);
        aw = __builtin_amdgcn_mfma_f32_32x32x16_bf16(a, wl, aw, 0, 0, 0);
        au = __builtin_amdgcn_mfma_f32_32x32x16_bf16(a, uh, au, 0, 0, 0);
        au = __builtin_amdgcn_mfma_f32_32x32x16_bf16(a, ul, au, 0, 0, 0);
        wh = whn; wl = wln; uh = uhn; ul = uln;
    }

    #pragma unroll
    for (int r = 0; r < 16; ++r) {
        int row = (r & 3) + 8 * (r >> 2) + 4 * half;
        Pe[(r0 + row) * 256 + col] = aw[r];
        Pn[(r0 + row) * 256 + col] = bf16_rne(au[r]);
    }
}

// 64 sorted edges/block, 512 threads = 8 waves. Single barrier; ids in registers.
// MODE 0: sorted holds eid (legacy; dependent eidx load).
// MODE 1: sorted holds int2{eid, src|dst<<12} (single-load startup).
// relu(Pe[src] + eattr@W1b + mb1) -> suffix-difference segmented reduce -> aggf
// (plain store for block-exclusive runs, fp32 atomics at window boundaries).
template<int MODE>
__global__ __launch_bounds__(512, 4)
void edge_kernel_t(const float* __restrict__ Pe,
                   const int*   __restrict__ eidx,
                   const int*   __restrict__ sorted,
                   const float* __restrict__ eattr,
                   const ushort_t* __restrict__ w1hi, const ushort_t* __restrict__ w1lo,
                   const float* __restrict__ b1,
                   float* __restrict__ aggf) {
    __shared__ ushort_t Xs[64 * EPAD];   // 8,704 B

    const int tid = threadIdx.x;
    const int b   = blockIdx.x >> 10;            // 1024 blocks per batch
    const int e0  = (blockIdx.x & 1023) * 64;
    const int wv = tid >> 6, ln = tid & 63;
    const int m32 = ln & 31, half = ln >> 5;
    const int col = wv * 32 + m32;

    // ---- per-lane edge ids ----
    int eid, src, dst;
    if (MODE == 1) {
        int2 p = ((const int2*)sorted)[(size_t)b * NE + e0 + ln];
        eid = p.x;
        src = p.y & 0xFFF;
        dst = p.y >> 12;
    } else {
        eid = sorted[(size_t)b * NE + e0 + ln];
        int2 ev = ((const int2*)eidx)[(size_t)b * NE + eid];
        src = min(max(ev.x, 0), NC - 1);
        dst = min(max(ev.y, 0), NC - 1);
    }

    // ---- W1b (eattr part, packed t=16..19) B fragments ----
    const ushort_t* ph = w1hi + ((size_t)(16 * 8 + wv) * 64 + ln) * 8;
    const ushort_t* pl = w1lo + ((size_t)(16 * 8 + wv) * 64 + ln) * 8;
    s16x8 bh0 = *(const s16x8*)ph;
    s16x8 bl0 = *(const s16x8*)pl;
    s16x8 bh1 = *(const s16x8*)(ph + 4096);
    s16x8 bl1 = *(const s16x8*)(pl + 4096);
    s16x8 bh2 = *(const s16x8*)(ph + 8192);
    s16x8 bl2 = *(const s16x8*)(pl + 8192);
    s16x8 bh3 = *(const s16x8*)(ph + 12288);
    s16x8 bl3 = *(const s16x8*)(pl + 12288);

    // ---- Pe gather (rows via shfl; 32 independent loads in flight) ----
    float t0[16], t1[16];
    {
        const float* pb = Pe + (size_t)b * NC * 256 + col;
        #pragma unroll
        for (int r = 0; r < 16; ++r) {
            int rw = (r & 3) + 8 * (r >> 2) + 4 * half;
            t0[r] = pb[(size_t)__shfl(src, rw, 64) * 256];
            t1[r] = pb[(size_t)__shfl(src, rw + 32, 64) * 256];
        }
    }

    // ---- stage eattr (64x64, gathered rows) as RNE bf16 ----
    {
        const int rowE = tid >> 3, c8 = tid & 7;
        int eidr = __shfl(eid, rowE, 64);
        const float4* arow = (const float4*)(eattr + ((size_t)b * NE + eidr) * EF);
        #pragma unroll
        for (int i = 0; i < 2; ++i) {
            int c = c8 + i * 8;
            float4 v = arow[c];
            *(uint2*)&Xs[rowE * EPAD + c * 4] =
                make_uint2(pk_bf16(v.x, v.y), pk_bf16(v.z, v.w));
        }
    }
    __syncthreads();   // the only barrier: eattr tile ready

    // ---- GEMM1: h1 = eattr @ W1b + b1, K=64 ----
    f32x16 A0, A1;
    {
        float bias = b1[col];
        #pragma unroll
        for (int r = 0; r < 16; ++r) { A0[r] = bias; A1[r] = bias; }
    }
    {
        int ao = m32 * EPAD + half * 8;
        s16x8 a0, a1;
        a0 = *(const s16x8*)&Xs[ao];      a1 = *(const s16x8*)&Xs[ao + 32 * EPAD];
        A0 = __builtin_amdgcn_mfma_f32_32x32x16_bf16(a0, bh0, A0, 0, 0, 0);
        A0 = __builtin_amdgcn_mfma_f32_32x32x16_bf16(a0, bl0, A0, 0, 0, 0);
        A1 = __builtin_amdgcn_mfma_f32_32x32x16_bf16(a1, bh0, A1, 0, 0, 0);
        A1 = __builtin_amdgcn_mfma_f32_32x32x16_bf16(a1, bl0, A1, 0, 0, 0);
        a0 = *(const s16x8*)&Xs[ao + 16]; a1 = *(const s16x8*)&Xs[ao + 16 + 32 * EPAD];
        A0 = __builtin_amdgcn_mfma_f32_32x32x16_bf16(a0, bh1, A0, 0, 0, 0);
        A0 = __builtin_amdgcn_mfma_f32_32x32x16_bf16(a0, bl1, A0, 0, 0, 0);
        A1 = __builtin_amdgcn_mfma_f32_32x32x16_bf16(a1, bh1, A1, 0, 0, 0);
        A1 = __builtin_amdgcn_mfma_f32_32x32x16_bf16(a1, bl1, A1, 0, 0, 0);
        a0 = *(const s16x8*)&Xs[ao + 32]; a1 = *(const s16x8*)&Xs[ao + 32 + 32 * EPAD];
        A0 = __builtin_amdgcn_mfma_f32_32x32x16_bf16(a0, bh2, A0, 0, 0, 0);
        A0 = __builtin_amdgcn_mfma_f32_32x32x16_bf16(a0, bl2, A0, 0, 0, 0);
        A1 = __builtin_amdgcn_mfma_f32_32x32x16_bf16(a1, bh2, A1, 0, 0, 0);
        A1 = __builtin_amdgcn_mfma_f32_32x32x16_bf16(a1, bl2, A1, 0, 0, 0);
        a0 = *(const s16x8*)&Xs[ao + 48]; a1 = *(const s16x8*)&Xs[ao + 48 + 32 * EPAD];
        A0 = __builtin_amdgcn_mfma_f32_32x32x16_bf16(a0, bh3, A0, 0, 0, 0);
        A0 = __builtin_amdgcn_mfma_f32_32x32x16_bf16(a0, bl3, A0, 0, 0, 0);
        A1 = __builtin_amdgcn_mfma_f32_32x32x16_bf16(a1, bh3, A1, 0, 0, 0);
        A1 = __builtin_amdgcn_mfma_f32_32x32x16_bf16(a1, bl3, A1, 0, 0, 0);
    }

    // ---- fold Pe[src] + relu ----
    #pragma unroll
    for (int r = 0; r < 16; ++r) {
        A0[r] = fmaxf(A0[r] + t0[r], 0.f);
        A1[r] = fmaxf(A1[r] + t1[r], 0.f);
    }

    // ---- suffix-difference segmented reduce over sorted dst runs ----
    // Runs with lo>0 && hi<32 are globally complete (sorted) -> plain store.
    {
        const int l31 = ln & 31;
        // rows 0..31 (A0)
        int dl = __shfl(dst, l31, 64);
        int dp = __shfl(dst, (l31 == 0) ? 0 : l31 - 1, 64);
        if (l31 == 0) dp = ~dl;
        unsigned m = (unsigned)__ballot(dl != dp);
        unsigned rem = m & ~1u;
        float prev = (((A0[0] + A0[1]) + (A0[2] + A0[3])) + ((A0[4] + A0[5]) + (A0[6] + A0[7])))
                   + (((A0[8] + A0[9]) + (A0[10] + A0[11])) + ((A0[12] + A0[13]) + (A0[14] + A0[15])));
        int lo = 0;
        while (lo < 32) {
            int hi = rem ? (int)__builtin_ctz(rem) : 32;
            rem &= rem - 1;
            int d = __shfl(dl, lo, 64);
            float shi = 0.f;
            if (hi < 32) {
                #pragma unroll
                for (int r = 0; r < 16; ++r) {
                    int row = (r & 3) + 8 * (r >> 2) + 4 * half;
                    shi += (row >= hi) ? A0[r] : 0.f;
                }
            }
            float s = prev - shi;
            prev = shi;
            s += __shfl_xor(s, 32, 64);
            if (ln < 32) {
                float* addr = &aggf[((size_t)b * NC + d) * HID + col];
                if (lo > 0 && hi < 32) *addr = s;     // block-exclusive run
                else atomicAdd(addr, s);              // window-boundary run
            }
            lo = hi;
        }
        // rows 32..63 (A1)
        dl = __shfl(dst, 32 + l31, 64);
        dp = __shfl(dst, 32 + ((l31 == 0) ? 0 : l31 - 1), 64);
        if (l31 == 0) dp = ~dl;
        m = (unsigned)__ballot(dl != dp);
        rem = m & ~1u;
        prev = (((A1[0] + A1[1]) + (A1[2] + A1[3])) + ((A1[4] + A1[5]) + (A1[6] + A1[7])))
             + (((A1[8] + A1[9]) + (A1[10] + A1[11])) + ((A1[12] + A1[13]) + (A1[14] + A1[15])));
        lo = 0;
        while (lo < 32) {
            int hi = rem ? (int)__builtin_ctz(rem) : 32;
            rem &= rem - 1;
            int d = __shfl(dl, lo, 64);
            float shi = 0.f;
            if (hi < 32) {
                #pragma unroll
                for (int r = 0; r < 16; ++r) {
                    int row = (r & 3) + 8 * (r >> 2) + 4 * half;
                    shi += (row >= hi) ? A1[r] : 0.f;
                }
            }
            float s = prev - shi;
            prev = shi;
            s += __shfl_xor(s, 32, 64);
            if (ln < 32) {
                float* addr = &aggf[((size_t)b * NC + d) * HID + col];
                if (lo > 0 && hi < 32) *addr = s;     // block-exclusive run
                else atomicAdd(addr, s);              // window-boundary run
            }
            lo = hi;
        }
    }
}

// 32 nodes/block, 512 threads = 8 waves; H tile in second LDS region
// (no barrier between GEMM1 and H-store).
__global__ __launch_bounds__(512, 4)
void node_kernel(const float* __restrict__ cell_x,
                 const float* __restrict__ aggf,
                 const float* __restrict__ counts,
                 const ushort_t* __restrict__ Pn,
                 const ushort_t* __restrict__ w2uhi, const ushort_t* __restrict__ w2ulo,
                 const float* __restrict__ bias2u,
                 const ushort_t* __restrict__ u2hi, const ushort_t* __restrict__ u2lo,
                 const float* __restrict__ b2,
                 const float* __restrict__ gamma, const float* __restrict__ beta,
                 float* __restrict__ out) {
    __shared__ ushort_t Us[32 * UPAD];   // [0,HOFF): agg bf16; [HOFF,2*HOFF): H bf16; hs fp32 overlay
    float* hs = (float*)Us;

    const int tid = threadIdx.x;
    const int b   = blockIdx.x >> 7;             // 128 blocks per batch
    const int r0  = (blockIdx.x & 127) * 32;
    const int wv = tid >> 6, ln = tid & 63;
    const int m32 = ln & 31, half = ln >> 5;
    const int col = wv * 32 + m32;

    // hoisted W2u (fused mW2@uW1b) B-prefetch
    const ushort_t* b1ph = w2uhi + ((size_t)wv * 64 + ln) * 8;
    const ushort_t* b1pl = w2ulo + ((size_t)wv * 64 + ln) * 8;
    s16x8 bhi = *(const s16x8*)b1ph;
    s16x8 blo = *(const s16x8*)b1pl;

    // ---- issue Pn gather early (consumed after GEMM1) ----
    ushort_t pnt[16];
    {
        const ushort_t* pb = Pn + ((size_t)b * NC + r0) * 256 + col;
        #pragma unroll
        for (int r = 0; r < 16; ++r) {
            int row = (r & 3) + 8 * (r >> 2) + 4 * half;
            pnt[r] = pb[(size_t)row * 256];
        }
    }

    // ---- stage aggH*inv (fp32 -> RNE bf16), 32 x 256 ----
    {
        const int row = tid >> 4, c8 = tid & 15;
        float inv = 1.0f / fmaxf(counts[b * NC + r0 + row], 1.0f);
        const float4* grow = (const float4*)(aggf + ((size_t)b * NC + r0 + row) * HID);
        #pragma unroll
        for (int i = 0; i < 4; ++i) {
            int c = c8 + i * 16;
            float4 g = grow[c];
            *(uint2*)&Us[row * HPAD + c * 4] =
                make_uint2(pk_bf16(g.x * inv, g.y * inv), pk_bf16(g.z * inv, g.w * inv));
        }
    }
    __syncthreads();   // barrier 1: agg tile ready

    // ---- GEMM1: acc = (aggH/deg) @ W2u + bias2u, K=256 ----
    f32x16 acc;
    {
        float bias = bias2u[col];
        #pragma unroll
        for (int r = 0; r < 16; ++r) acc[r] = bias;
    }
    #pragma unroll 2
    for (int t = 0; t < 16; ++t) {
        int tn1 = (t + 1 < 16) ? t + 1 : 15;
        s16x8 bhin = *(const s16x8*)(b1ph + (size_t)tn1 * 4096);
        s16x8 blon = *(const s16x8*)(b1pl + (size_t)tn1 * 4096);
        s16x8 a = *(const s16x8*)&Us[m32 * HPAD + t * 16 + half * 8];
        acc = __builtin_amdgcn_mfma_f32_32x32x16_bf16(a, bhi, acc, 0, 0, 0);
        acc = __builtin_amdgcn_mfma_f32_32x32x16_bf16(a, blo, acc, 0, 0, 0);
        bhi = bhin; blo = blon;
    }

    // ---- add Pn (cell_x @ uW1a half) ----
    #pragma unroll
    for (int r = 0; r < 16; ++r) acc[r] += bf16_to_f(pnt[r]);

    // hoisted uW2 B-prefetch
    const ushort_t* b2ph = u2hi + ((size_t)wv * 64 + ln) * 8;
    const ushort_t* b2pl = u2lo + ((size_t)wv * 64 + ln) * 8;
    bhi = *(const s16x8*)b2ph;
    blo = *(const s16x8*)b2pl;

    // ---- relu + store H to region 2 (no barrier needed before store) ----
    #pragma unroll
    for (int r = 0; r < 16; ++r) {
        int row = (r & 3) + 8 * (r >> 2) + 4 * half;
        Us[HOFF + row * HPAD + col] = bf16_rne(fmaxf(acc[r], 0.f));
    }
    __syncthreads();   // barrier 2: H ready

    // ---- issue residual cell_x loads early (consumed after GEMM2) ----
    float cxt[16];
    #pragma unroll
    for (int r = 0; r < 16; ++r) {
        int row = (r & 3) + 8 * (r >> 2) + 4 * half;
        cxt[r] = cell_x[((size_t)b * NC + r0 + row) * HID + col];
    }

    // ---- GEMM2: o = hidden @ uW2 + ub2, K=256 ----
    f32x16 c2;
    {
        float bias = b2[col];
        #pragma unroll
        for (int r = 0; r < 16; ++r) c2[r] = bias;
    }
    #pragma unroll 2
    for (int t = 0; t < 16; ++t) {
        int tn1 = (t + 1 < 16) ? t + 1 : 15;
        s16x8 bhin = *(const s16x8*)(b2ph + (size_t)tn1 * 4096);
        s16x8 blon = *(const s16x8*)(b2pl + (size_t)tn1 * 4096);
        s16x8 a = *(const s16x8*)&Us[HOFF + m32 * HPAD + t * 16 + half * 8];
        c2 = __builtin_amdgcn_mfma_f32_32x32x16_bf16(a, bhi, c2, 0, 0, 0);
        c2 = __builtin_amdgcn_mfma_f32_32x32x16_bf16(a, blo, c2, 0, 0, 0);
        bhi = bhin; blo = blon;
    }
    __syncthreads();   // barrier 3: H dead; hs overlay may overwrite whole pool

    // ---- residual: h = cell_x + o ----
    #pragma unroll
    for (int r = 0; r < 16; ++r) {
        int row = (r & 3) + 8 * (r >> 2) + 4 * half;
        hs[row * HSF + col] = c2[r] + cxt[r];
    }
    __syncthreads();   // barrier 4: hs ready

    // ---- LayerNorm per row: wave wv handles rows wv*4..+3 ----
    #pragma unroll
    for (int i = 0; i < 4; ++i) {
        int r = wv * 4 + i;
        float v[4];
        float s = 0.f, q = 0.f;
        #pragma unroll
        for (int j = 0; j < 4; ++j) {
            v[j] = hs[r * HSF + ln + 64 * j];
            s += v[j];
            q = fmaf(v[j], v[j], q);
        }
        #pragma unroll
        for (int off = 32; off > 0; off >>= 1) {
            s += __shfl_xor(s, off, 64);
            q += __shfl_xor(q, off, 64);
        }
        float mu = s * (1.0f / HID);
        float var = q * (1.0f / HID) - mu * mu;
        float rs = rsqrtf(var + EPSV);
        float* orow = out + ((size_t)b * NC + r0 + r) * HID;
        #pragma unroll
        for (int j = 0; j < 4; ++j) {
            int c = ln + 64 * j;
            orow[c] = (v[j] - mu) * rs * gamma[c] + beta[c];
        }
    }
}

extern "C" void kernel_launch(void* const* d_in, const int* in_sizes, int n_in,
                              void* d_out, int out_size, void* d_ws, size_t ws_size,
                              hipStream_t stream) {
    const float* cell_x = (const float*)d_in[0];
    const int*   eidx   = (const int*)d_in[1];
    const float* eattr  = (const float*)d_in[2];
    const float* mW1    = (const float*)d_in[3];
    const float* mb1    = (const float*)d_in[4];
    const float* mW2    = (const float*)d_in[5];
    const float* mb2    = (const float*)d_in[6];
    const float* uW1    = (const float*)d_in[7];
    const float* ub1    = (const float*)d_in[8];
    const float* uW2    = (const float*)d_in[9];
    const float* ub2    = (const float*)d_in[10];
    const float* gamma  = (const float*)d_in[11];
    const float* beta   = (const float*)d_in[12];
    float* out = (float*)d_out;

    // sequential workspace layout; sorted is int (1 MB) or int2 payload (2 MB)
    // total: 44.50 MB (legacy, proven) / 45.55 MB (payload)
    char* p = (char*)d_ws;
    float* aggf = (float*)p;          p += (size_t)BSZ * NC * HID * 4;
    float* counts = (float*)p;        p += (size_t)BSZ * NC * 4;
    int* filled = (int*)p;            p += (size_t)BSZ * NC * 4;
    char* sorted_base = p;

    // probe payload-layout size
    size_t tail = (size_t)KIN * HID * 2 * 2      // w1 packs
                + (size_t)HID * HID * 2 * 6      // u1/u2/w2u packs
                + (size_t)HID * HID * 4          // W2u raw
                + (size_t)HID * 4                // bias2u
                + (size_t)BSZ * NC * 256 * 4     // Pe
                + (size_t)BSZ * NC * 256 * 2;    // Pn
    size_t need_payload = (size_t)(sorted_base - (char*)d_ws) + (size_t)BSZ * NE * 8 + tail;
    int payload = (ws_size >= need_payload) ? 1 : 0;

    p = sorted_base + (size_t)BSZ * NE * (payload ? 8 : 4);
    int* sorted = (int*)sorted_base;
    ushort_t* w1hi = (ushort_t*)p;    p += (size_t)KIN * HID * 2;
    ushort_t* w1lo = (ushort_t*)p;    p += (size_t)KIN * HID * 2;
    ushort_t* u1hi = (ushort_t*)p;    p += (size_t)HID * HID * 2;
    ushort_t* u1lo = (ushort_t*)p;    p += (size_t)HID * HID * 2;
    ushort_t* u2hi = (ushort_t*)p;    p += (size_t)HID * HID * 2;
    ushort_t* u2lo = (ushort_t*)p;    p += (size_t)HID * HID * 2;
    ushort_t* w2uhi = (ushort_t*)p;   p += (size_t)HID * HID * 2;
    ushort_t* w2ulo = (ushort_t*)p;   p += (size_t)HID * HID * 2;
    float* W2u = (float*)p;           p += (size_t)HID * HID * 4;
    float* bias2u = (float*)p;        p += (size_t)HID * 4;
    float* Pe = (float*)p;            p += (size_t)BSZ * NC * 256 * 4;
    ushort_t* Pn = (ushort_t*)p;

    // zero aggf + counts + filled (contiguous at d_ws start) via async memset
    size_t zbytes = (size_t)BSZ * NC * HID * 4 + (size_t)BSZ * NC * 4 + (size_t)BSZ * NC * 4;
    hipMemsetAsync(d_ws, 0, zbytes, stream);

    prep_kernel<<<PACK1B + FUSEB + 1 + HISTB, 256, 0, stream>>>(
        mW1, uW1, uW2, mW2, ub1, mb2,
        w1hi, w1lo, u1hi, u1lo, u2hi, u2lo, W2u, bias2u, eidx, counts);
    hp_kernel<<<1040, 512, 0, stream>>>(eidx, counts, filled, sorted, payload, cell_x,
                                        w1hi, w1lo, u1hi, u1lo, Pe, Pn,
                                        W2u, w2uhi, w2ulo);
    if (payload) {
        edge_kernel_t<1><<<BSZ * NE / 64, 512, 0, stream>>>(Pe, eidx, sorted, eattr,
                                                            w1hi, w1lo, mb1, aggf);
    } else {
        edge_kernel_t<0><<<BSZ * NE / 64, 512, 0, stream>>>(Pe, eidx, sorted, eattr,
                                                            w1hi, w1lo, mb1, aggf);
    }
    node_kernel<<<BSZ * NC / 32, 512, 0, stream>>>(cell_x, aggf, counts, Pn,
                                                   w2uhi, w2ulo, bias2u,
                                                   u2hi, u2lo, ub2,
                                                   gamma, beta, out);
}